// Round 4
// baseline (2739.935 us; speedup 1.0000x reference)
//
#include <hip/hip_runtime.h>
#include <cstdint>

#define NS 2048      // states S
#define NE 65536     // arcs E
#define ND 2048      // pdfs D
#define NB 32        // batch
#define NT 500       // frames
#define NGROUPS 32   // 64-state groups == state partitions
#define ELLCAP (2*NE)   // uint4 entries (expected padded total ~98K < 131072)
#define LEAKYF 0.1f
#define NSP 32       // state partitions (64 states each)
#define NBGRP 8      // batch groups (4 batches each)

// ws byte offsets
#define WS_COUNTS   0
#define WS_CURSOR   8192
#define WS_WIDTHS   16384
#define WS_GBASE    16512
#define WS_FLAGS    17408      // 8 bg x 32 x u32 (one 128B line per bg)
#define WS_ALBUF    18432      // 2 * 8bg * 2048 * 4 floats = 1 MB
#define WS_ARC      1067008    // ELLCAP * 16B = 2 MB

// ---- per-op device-coherent (L3) access, NO cache-wide fences ----
__device__ __forceinline__ void st_pair(float* p, float a, float b) {
    union { float f[2]; unsigned long long u; } q; q.f[0] = a; q.f[1] = b;
    __hip_atomic_store(reinterpret_cast<unsigned long long*>(p), q.u,
                       __ATOMIC_RELAXED, __HIP_MEMORY_SCOPE_AGENT);
}
__device__ __forceinline__ float2 ld_pair(const float* p) {
    unsigned long long u = __hip_atomic_load(
        reinterpret_cast<const unsigned long long*>(p),
        __ATOMIC_RELAXED, __HIP_MEMORY_SCOPE_AGENT);
    union { unsigned long long u; float f[2]; } q; q.u = u;
    return make_float2(q.f[0], q.f[1]);
}

__device__ __forceinline__ float4 wave_reduce4(float4 v) {
    #pragma unroll
    for (int off = 32; off > 0; off >>= 1) {
        v.x += __shfl_down(v.x, off, 64);
        v.y += __shfl_down(v.y, off, 64);
        v.z += __shfl_down(v.z, off, 64);
        v.w += __shfl_down(v.w, off, 64);
    }
    return v;
}

__global__ void k_init(const float* __restrict__ log_init, float* albuf,
                       uint32_t* counts, uint32_t* cursor, uint4* arc,
                       uint32_t* flags, float* out) {
    int tid = blockIdx.x * blockDim.x + threadIdx.x;
    int n = blockDim.x * gridDim.x;
    for (int i = tid; i < NS; i += n) { counts[i] = 0u; cursor[i] = 0u; }
    for (int i = tid; i < ELLCAP; i += n) arc[i] = make_uint4(0u, 0u, 0u, 0u);
    for (int i = tid; i < NBGRP * NS * 4; i += n) {
        int s = (i >> 2) & (NS - 1);
        albuf[i] = __expf(log_init[s]);   // buf0: [bg][s][4bb]
    }
    for (int i = tid; i < NBGRP * 32; i += n) flags[i] = 0u;
    if (tid == 0) out[0] = 0.0f;
}

__global__ void k_count(const int* __restrict__ to_state, uint32_t* counts) {
    int e = blockIdx.x * blockDim.x + threadIdx.x;
    if (e < NE) atomicAdd(&counts[to_state[e]], 1u);
}

__global__ void k_widths(const uint32_t* __restrict__ counts, uint32_t* widths, uint32_t* gbase) {
    int g = threadIdx.x;
    if (g < NGROUPS) {
        uint32_t w = 0u;
        for (int i = 0; i < 64; ++i) w = max(w, counts[g*64 + i]);
        widths[g] = w;
    }
    __syncthreads();
    if (threadIdx.x == 0) {
        uint32_t acc = 0u;
        for (int g2 = 0; g2 < NGROUPS; ++g2) { gbase[g2] = acc; acc += widths[g2] * 64u; }
        gbase[NGROUPS] = acc;
    }
}

__global__ void k_scatter(const int* __restrict__ from_state, const int* __restrict__ to_state,
                          const int* __restrict__ pdf_ids, const float* __restrict__ log_w,
                          const float* __restrict__ log_init,
                          const uint32_t* __restrict__ gbase, uint32_t* cursor, uint4* arc) {
    int e = blockIdx.x * blockDim.x + threadIdx.x;
    if (e >= NE) return;
    int s = to_state[e];
    int g = s >> 6;
    uint32_t slot = atomicAdd(&cursor[s], 1u);
    uint32_t pos = gbase[g] + slot * 64u + (uint32_t)(s & 63);
    int fs = from_state[e];
    uint32_t meta = (uint32_t)fs | ((uint32_t)pdf_ids[e] << 16);
    float w  = __expf(log_w[e]);
    float w2 = LEAKYF * __expf(log_init[fs]) * w;   // leaky-term weight
    arc[pos] = make_uint4(meta, __float_as_uint(w), __float_as_uint(w2), 0u);
}

// 256 persistent WGs: bid = bg*32 + sp. bg owns 4 batches; sp owns 64 dest states.
// LDS tables are float4 (batch-interleaved): one b128 gather serves 4 batches.
// Raw alpha gathered; normalization folded into epilogue: new_a = invT*s1 + s2.
__global__ __launch_bounds__(1024, 1) void k_fwd(
    const float* __restrict__ x, const float* __restrict__ log_init,
    const float* __restrict__ log_final,
    const uint4* __restrict__ arc, const uint32_t* __restrict__ widths,
    const uint32_t* __restrict__ gbase,
    float* __restrict__ albuf, uint32_t* __restrict__ flags, float* out)
{
    __shared__ __align__(16) float4 aLDS[NS];      // 32 KB raw alpha [s][4bb]
    __shared__ __align__(16) float4 Xs[2][ND];     // 64 KB exp(x) double-buffered
    __shared__ float pt[16][4][72];                // 18 KB wave partials (pad 72: conflict-free)
    __shared__ float4 red[16];

    const int tid  = threadIdx.x;
    const int sp   = blockIdx.x & 31;
    const int bg   = blockIdx.x >> 5;
    const int lane = tid & 63;
    const int wid  = tid >> 6;

    const float* xb = x + (size_t)(bg * 4) * NT * ND;

    // Xs[0] for t=0
    {
        float p0[4], p1[4];
        #pragma unroll
        for (int bb = 0; bb < 4; ++bb) {
            p0[bb] = xb[(size_t)bb * NT * ND + tid];
            p1[bb] = xb[(size_t)bb * NT * ND + tid + 1024];
        }
        Xs[0][tid]        = make_float4(__expf(p0[0]), __expf(p0[1]), __expf(p0[2]), __expf(p0[3]));
        Xs[0][tid + 1024] = make_float4(__expf(p1[0]), __expf(p1[1]), __expf(p1[2]), __expf(p1[3]));
    }

    const uint32_t gb = gbase[sp];
    const int wd = (int)widths[sp];
    const uint4* ap = arc + gb + lane;        // slot i at ap[i*64]
    uint32_t* myflags = flags + bg * 32;

    float4 C4 = make_float4(0.f, 0.f, 0.f, 0.f);

    for (int t = 0; t < NT; ++t) {
        const int cb = t & 1;
        const float* cbuf = albuf + ((size_t)cb * NBGRP + bg) * (NS * 4);
        float*       nbuf = albuf + ((size_t)(cb ^ 1) * NBGRP + bg) * (NS * 4);

        // coherent raw-alpha loads (16B per state via 2x b64)
        float2 a0 = ld_pair(cbuf + (size_t)tid * 4);
        float2 a1 = ld_pair(cbuf + (size_t)tid * 4 + 2);
        float2 a2 = ld_pair(cbuf + (size_t)(tid + 1024) * 4);
        float2 a3 = ld_pair(cbuf + (size_t)(tid + 1024) * 4 + 2);

        // x(t+1) prefetch (latency hidden under this whole step)
        float px[8];
        const bool pf = (t + 1 < NT);
        if (pf) {
            #pragma unroll
            for (int bb = 0; bb < 4; ++bb) {
                px[bb]     = xb[(size_t)bb * NT * ND + (size_t)(t + 1) * ND + tid];
                px[bb + 4] = xb[(size_t)bb * NT * ND + (size_t)(t + 1) * ND + tid + 1024];
            }
        }

        float4 va0 = make_float4(a0.x, a0.y, a1.x, a1.y);
        float4 va1 = make_float4(a2.x, a2.y, a3.x, a3.y);
        aLDS[tid]        = va0;
        aLDS[tid + 1024] = va1;
        float4 part = make_float4(va0.x + va1.x, va0.y + va1.y, va0.z + va1.z, va0.w + va1.w);
        part = wave_reduce4(part);
        if (lane == 0) red[wid] = part;
        __syncthreads();                               // (B) aLDS + Xs(t) + red ready

        // T4: wave-local tree (1 LDS read + shfl, off the gather critical path)
        float4 rv = red[lane & 15];
        #pragma unroll
        for (int off = 8; off > 0; off >>= 1) {
            rv.x += __shfl_down(rv.x, off, 16);
            rv.y += __shfl_down(rv.y, off, 16);
            rv.z += __shfl_down(rv.z, off, 16);
            rv.w += __shfl_down(rv.w, off, 16);
        }
        float4 T4;
        T4.x = __shfl(rv.x, 0, 16);
        T4.y = __shfl(rv.y, 0, 16);
        T4.z = __shfl(rv.z, 0, 16);
        T4.w = __shfl(rv.w, 0, 16);
        float4 iT = make_float4(1.f/T4.x, 1.f/T4.y, 1.f/T4.z, 1.f/T4.w);
        C4.x += __logf(T4.x); C4.y += __logf(T4.y);
        C4.z += __logf(T4.z); C4.w += __logf(T4.w);

        // arc pass: 2 b128 gathers per arc serve 4 batches
        float4 s1 = make_float4(0.f,0.f,0.f,0.f);
        float4 s2 = make_float4(0.f,0.f,0.f,0.f);
        for (int i = wid; i < wd; i += 16) {
            uint4 A = ap[(size_t)i * 64];
            const float w  = __uint_as_float(A.y);
            const float w2 = __uint_as_float(A.z);
            const int src = (int)(A.x & 0xFFFFu);
            const int pdf = (int)(A.x >> 16);
            float4 av = aLDS[src];
            float4 xv = Xs[cb][pdf];
            s1.x += av.x * (w * xv.x);  s1.y += av.y * (w * xv.y);
            s1.z += av.z * (w * xv.z);  s1.w += av.w * (w * xv.w);
            s2.x += w2 * xv.x;          s2.y += w2 * xv.y;
            s2.z += w2 * xv.z;          s2.w += w2 * xv.w;
        }
        pt[wid][0][lane] = iT.x * s1.x + s2.x;
        pt[wid][1][lane] = iT.y * s1.y + s2.y;
        pt[wid][2][lane] = iT.z * s1.z + s2.z;
        pt[wid][3][lane] = iT.w * s1.w + s2.w;

        if (pf) {   // exp + store Xs(t+1) into the other buffer
            Xs[cb ^ 1][tid]        = make_float4(__expf(px[0]), __expf(px[1]), __expf(px[2]), __expf(px[3]));
            Xs[cb ^ 1][tid + 1024] = make_float4(__expf(px[4]), __expf(px[5]), __expf(px[6]), __expf(px[7]));
        }
        __syncthreads();                               // (C) pt ready

        // reduce 16 wave-partials, coherent-store my 64 states x 4 batches
        if (tid < 128) {
            const int s  = tid >> 1;
            const int bb = (tid & 1) * 2;
            float r0 = 0.f, r1 = 0.f;
            #pragma unroll
            for (int w3 = 0; w3 < 16; ++w3) {
                r0 += pt[w3][bb][s];
                r1 += pt[w3][bb + 1][s];
            }
            st_pair(nbuf + (size_t)(sp * 64 + s) * 4 + bb, r0, r1);
        }
        __syncthreads();                               // (D) all stores drained (vmcnt 0 per wave)

        if (tid == 0)
            __hip_atomic_store(&myflags[sp], (uint32_t)(t + 1),
                               __ATOMIC_RELAXED, __HIP_MEMORY_SCOPE_AGENT);
        if (wid == 0) {
            const uint32_t tgt = (uint32_t)(t + 1);
            while (__hip_atomic_load(&myflags[lane & 31], __ATOMIC_RELAXED,
                                     __HIP_MEMORY_SCOPE_AGENT) < tgt)
                __builtin_amdgcn_s_sleep(1);
        }
        __syncthreads();                               // (E)
    }

    // epilogue: sp==0 WG of each batch-group (final alpha in buf0, NT even)
    if (sp == 0) {
        const float* fbuf = albuf + (size_t)bg * (NS * 4);
        float2 a0 = ld_pair(fbuf + (size_t)tid * 4);
        float2 a1 = ld_pair(fbuf + (size_t)tid * 4 + 2);
        float2 a2 = ld_pair(fbuf + (size_t)(tid + 1024) * 4);
        float2 a3 = ld_pair(fbuf + (size_t)(tid + 1024) * 4 + 2);
        float f0 = __expf(log_final[tid]);
        float f1 = __expf(log_final[tid + 1024]);
        float4 part;
        part.x = a0.x * f0 + a2.x * f1;
        part.y = a0.y * f0 + a2.y * f1;
        part.z = a1.x * f0 + a3.x * f1;
        part.w = a1.y * f0 + a3.y * f1;
        part = wave_reduce4(part);
        if (lane == 0) red[wid] = part;
        __syncthreads();
        if (tid == 0) {
            float4 T4 = red[0];
            #pragma unroll
            for (int j = 1; j < 16; ++j) {
                float4 r = red[j];
                T4.x += r.x; T4.y += r.y; T4.z += r.z; T4.w += r.w;
            }
            float obj = (__logf(T4.x) + C4.x) + (__logf(T4.y) + C4.y)
                      + (__logf(T4.z) + C4.z) + (__logf(T4.w) + C4.w);
            atomicAdd(out, -obj);
        }
    }
}

extern "C" void kernel_launch(void* const* d_in, const int* in_sizes, int n_in,
                              void* d_out, int out_size, void* d_ws, size_t ws_size,
                              hipStream_t stream) {
    const float* x         = (const float*)d_in[0];
    const float* log_w     = (const float*)d_in[1];
    const float* log_init  = (const float*)d_in[2];
    const float* log_final = (const float*)d_in[3];
    const int*   from_st   = (const int*)d_in[4];
    const int*   to_st     = (const int*)d_in[5];
    const int*   pdf_ids   = (const int*)d_in[6];
    float* out = (float*)d_out;

    uint8_t* ws = (uint8_t*)d_ws;
    uint32_t* counts  = (uint32_t*)(ws + WS_COUNTS);
    uint32_t* cursor  = (uint32_t*)(ws + WS_CURSOR);
    uint32_t* widths  = (uint32_t*)(ws + WS_WIDTHS);
    uint32_t* gbase   = (uint32_t*)(ws + WS_GBASE);
    uint32_t* flags   = (uint32_t*)(ws + WS_FLAGS);
    float*    albuf   = (float*)(ws + WS_ALBUF);
    uint4*    arc     = (uint4*)(ws + WS_ARC);

    k_init   <<<512, 256, 0, stream>>>(log_init, albuf, counts, cursor, arc, flags, out);
    k_count  <<<NE/256, 256, 0, stream>>>(to_st, counts);
    k_widths <<<1, 64, 0, stream>>>(counts, widths, gbase);
    k_scatter<<<NE/256, 256, 0, stream>>>(from_st, to_st, pdf_ids, log_w, log_init,
                                          gbase, cursor, arc);
    k_fwd    <<<NSP*NBGRP, 1024, 0, stream>>>(x, log_init, log_final, arc, widths, gbase,
                                              albuf, flags, out);
}